// Round 1
// baseline (275.053 us; speedup 1.0000x reference)
//
#include <hip/hip_runtime.h>
#include <stdint.h>

// Problem constants (LieAction): B=16384, K=64, M=6, NUM_ACTIONS=16
#define BATCH 16384
#define KSUB 64
#define MDIM 6
#define MM 36            // floats per (b,k) block
#define NACT 16
#define F4PB 9           // float4 per block
#define WGT 64           // threads per wg == blocks per wg (single wave)

typedef float f32x4 __attribute__((ext_vector_type(4)));
typedef float f32x2 __attribute__((ext_vector_type(2)));

// Kernel 1: R[a][k] = expm( act_params[a,k] * (L_k - L_k^T) ), fp32 Taylor n<=10.
// ||A||_inf <~ 0.05 -> truncation error ~1e-12. ~5 us, negligible.
__global__ void expm_table_kernel(const float* __restrict__ act_params, // [NACT,KSUB]
                                  const float* __restrict__ basis,      // [KSUB,36]
                                  float* __restrict__ Rtab)             // [NACT*KSUB,36]
{
    int gid = blockIdx.x * blockDim.x + threadIdx.x;
    if (gid >= NACT * KSUB) return;
    int a = gid / KSUB;
    int k = gid - a * KSUB;

    float L[MM];
#pragma unroll
    for (int i = 0; i < MM; ++i) L[i] = basis[k * MM + i];
    float p = act_params[a * KSUB + k];

    float A[MM];
#pragma unroll
    for (int i = 0; i < MDIM; ++i)
#pragma unroll
        for (int j = 0; j < MDIM; ++j)
            A[i * MDIM + j] = p * (L[i * MDIM + j] - L[j * MDIM + i]);

    float E[MM], T[MM];
#pragma unroll
    for (int i = 0; i < MM; ++i) { E[i] = 0.f; T[i] = 0.f; }
#pragma unroll
    for (int i = 0; i < MDIM; ++i) { E[i * MDIM + i] = 1.f; T[i * MDIM + i] = 1.f; }

    for (int n = 1; n <= 10; ++n) {
        float Tn[MM];
        float inv = 1.0f / (float)n;
#pragma unroll
        for (int i = 0; i < MDIM; ++i)
#pragma unroll
            for (int l = 0; l < MDIM; ++l) {
                float s = 0.f;
#pragma unroll
                for (int j = 0; j < MDIM; ++j)
                    s += A[i * MDIM + j] * T[j * MDIM + l];
                Tn[i * MDIM + l] = s * inv;
            }
#pragma unroll
        for (int i = 0; i < MM; ++i) { T[i] = Tn[i]; E[i] += Tn[i]; }
    }
#pragma unroll
    for (int i = 0; i < MM; ++i) Rtab[gid * MM + i] = E[i];
}

// Kernel 2: out[b,k] = R[act[b],k] @ G[b,k]  (6x6 @ 6x6, fp32)
// One 64-thread (single-wave) wg per batch row b: thread k owns block (b,k).
//
// LDS layout: LINEAR pitch-36 floats (no pad). 36 dwords == 4 (mod 32), i.e.
// exactly one lane's 16B access width, so the stride-144B per-thread b128/b64
// accesses spread 8 lanes per bank-quad — same distribution as contiguous ->
// conflict-free. Enables b128 everywhere AND global_load_lds direct staging
// (which requires a linear, unpadded destination).
//
// Register budget: R(36) + O(36) + g-row(6) + addr ~= 95 VGPR — fits the
// 128-cap from __launch_bounds__(64,4) with no spill. LDS 9216 B -> 16 wg/CU.
__global__ __launch_bounds__(WGT, 4) void apply_kernel(
    const f32x4* __restrict__ gf4,           // B*K*9 float4
    const int* __restrict__ act,             // [B] int32
    const float* __restrict__ Rtab,          // [NACT*KSUB*36] f32
    f32x4* __restrict__ out4)                // B*K*9 float4
{
    __shared__ f32x4 lds4[WGT * F4PB];       // 9216 B, linear
    const int tid = threadIdx.x;
    const int b = blockIdx.x;
    const size_t base4 = (size_t)b * (WGT * F4PB);

    // 1) async global->LDS stage: issue i writes lane l's 16B to lds4[i*64+l].
    //    No VGPR round-trip, no ds_write instructions.
#pragma unroll
    for (int i = 0; i < F4PB; ++i) {
        __builtin_amdgcn_global_load_lds(
            (const __attribute__((address_space(1))) uint32_t*)(gf4 + base4 + (i << 6) + tid),
            (__attribute__((address_space(3))) uint32_t*)(&lds4[i << 6]),
            16, 0, 0);
    }

    // 2) R prefetch overlapping the DMA: lane tid -> row (act[b]*64 + tid).
    //    act[b] is wg-uniform -> scalar load; rows 16B-aligned (144 B each).
    const int a = act[b];                    // s_load
    const f32x4* R4 = (const f32x4*)(Rtab + (size_t)((a << 6) + tid) * MM);
    float R[MM];
#pragma unroll
    for (int q = 0; q < F4PB; ++q) {
        f32x4 rv = R4[q];
        R[4 * q + 0] = rv.x; R[4 * q + 1] = rv.y;
        R[4 * q + 2] = rv.z; R[4 * q + 3] = rv.w;
    }

    __syncthreads();                         // vmcnt(0): DMA (+R) complete; single wave -> cheap

    // 3) O = R @ G. Stream G one row j at a time from this thread's own LDS
    //    slice (3x ds_read_b64, 8B-aligned, conflict-free) — keeps only 6 G
    //    floats live instead of 36.
    const f32x2* grow = (const f32x2*)(&lds4[tid * F4PB]);
    float O[MM];
#pragma unroll
    for (int j = 0; j < MDIM; ++j) {
        f32x2 ga = grow[3 * j + 0];
        f32x2 gb = grow[3 * j + 1];
        f32x2 gc = grow[3 * j + 2];
        float g0 = ga.x, g1 = ga.y, g2 = gb.x, g3 = gb.y, g4 = gc.x, g5 = gc.y;
        if (j == 0) {
#pragma unroll
            for (int i = 0; i < MDIM; ++i) {
                float r = R[i * MDIM + 0];
                O[i * MDIM + 0] = r * g0; O[i * MDIM + 1] = r * g1;
                O[i * MDIM + 2] = r * g2; O[i * MDIM + 3] = r * g3;
                O[i * MDIM + 4] = r * g4; O[i * MDIM + 5] = r * g5;
            }
        } else {
#pragma unroll
            for (int i = 0; i < MDIM; ++i) {
                float r = R[i * MDIM + j];
                O[i * MDIM + 0] = fmaf(r, g0, O[i * MDIM + 0]);
                O[i * MDIM + 1] = fmaf(r, g1, O[i * MDIM + 1]);
                O[i * MDIM + 2] = fmaf(r, g2, O[i * MDIM + 2]);
                O[i * MDIM + 3] = fmaf(r, g3, O[i * MDIM + 3]);
                O[i * MDIM + 4] = fmaf(r, g4, O[i * MDIM + 4]);
                O[i * MDIM + 5] = fmaf(r, g5, O[i * MDIM + 5]);
            }
        }
    }

    // 4) write O back to own slice (b128 x9). Each thread reads/writes ONLY
    //    its own 144B slice in phase 3/4 -> no barrier needed before this.
    f32x4* orow = (f32x4*)(&lds4[tid * F4PB]);
#pragma unroll
    for (int q = 0; q < F4PB; ++q) {
        f32x4 v;
        v.x = O[4 * q + 0]; v.y = O[4 * q + 1];
        v.z = O[4 * q + 2]; v.w = O[4 * q + 3];
        orow[q] = v;
    }
    __syncthreads();                         // O visible wave-wide for gather

    // 5) coalesced nontemporal gather-store (b128 contiguous LDS reads)
#pragma unroll
    for (int i = 0; i < F4PB; ++i) {
        int p4 = (i << 6) + tid;
        __builtin_nontemporal_store(lds4[p4], &out4[base4 + p4]);
    }
}

extern "C" void kernel_launch(void* const* d_in, const int* in_sizes, int n_in,
                              void* d_out, int out_size, void* d_ws, size_t ws_size,
                              hipStream_t stream) {
    const float* gf    = (const float*)d_in[0];  // group_feats f32 [B, K*36]
    const int*   act   = (const int*)d_in[1];    // [B] int32
    const float* ap    = (const float*)d_in[2];  // act_params f32 [16,64]
    const float* basis = (const float*)d_in[3];  // lie_alg_basis f32 [64,36]

    float* Rtab = (float*)d_ws;   // 16*64*36*4 = 147456 B of ws

    expm_table_kernel<<<16, 64, 0, stream>>>(ap, basis, Rtab);

    apply_kernel<<<BATCH, WGT, 0, stream>>>((const f32x4*)gf, act, Rtab,
                                            (f32x4*)d_out);
}